// Round 2
// baseline (125.310 us; speedup 1.0000x reference)
//
#include <hip/hip_runtime.h>
#include <stdint.h>

#define T_ 256
#define B_ 8
#define E_ 512
#define H_ 32
#define HD_ 16
#define EXP_ 512
#define S_ 768          // T_ + EXP_
#define M_ 2048         // T_ * B_
#define SMOOTH_ 20.0f
#define VSTR 776        // V^T LDS row stride (bf16); 776*2=1552 ≡ 16 mod 128 -> conflict-free b128
#define OSTR 20         // O-combine LDS row stride (f32)
#define LWSTR 36        // LAW stage LDS row stride (f32)
#define LOG2E_ 1.44269504f
#define MB0_  (-100.988655f)   // -70 * log2e

typedef __attribute__((ext_vector_type(8)))  short bf16x8;
typedef __attribute__((ext_vector_type(4)))  float f32x4;
typedef __attribute__((ext_vector_type(16))) float f32x16;
typedef __attribute__((ext_vector_type(2)))  unsigned int uint32x2;

// round-half-up pack: two fp32 -> dword of two bf16 (lo=a, hi=b)
__device__ __forceinline__ unsigned int pku(float a, float b)
{
    return ((__float_as_uint(a) + 0x8000u) >> 16) |
           ((__float_as_uint(b) + 0x8000u) & 0xFFFF0000u);
}
__device__ __forceinline__ ushort bf1(float a)   // RNE
{
    unsigned int u = __float_as_uint(a);
    u = u + 0x7FFFu + ((u >> 16) & 1u);
    return (ushort)(u >> 16);
}

union U16 { uint4 u; bf16x8 v; };

// ---------------------------------------------------------------------------
// Fused QKV-GEMM + attention, v14: swapped-QK^T in-register softmax.
// Phase B computes mfma(K,Q) so the score tile is [s-regs][t-lanes]:
//   - z is a scalar per lane (one shfl_xor(32) reduce)
//   - P->PV via 8 pku + 4 permlane32_swap per s-tile (no LDS round trip)
//   - PV uses mfma_32x32x16 (A=P, B=V), d=16 of 32 cols used
//   - LAW tile (32x32) staged per-wave in padded LDS, pipelined 1 tile ahead
// XCD-aware decode b = bid&7 kept from v13 (FETCH 42.7 -> 17.5 MB).
// LDS map: Ks 0..24576 | Vt ..49408 | Qi ..57600 | msf ..60672 | LAW ..134400
// ---------------------------------------------------------------------------
__global__ __launch_bounds__(1024, 4)
void qkv_attn_kernel(const float* __restrict__ X,
                     const float* __restrict__ Wq, const float* __restrict__ Wk,
                     const float* __restrict__ Wv,
                     const float* __restrict__ bq, const float* __restrict__ bv,
                     const float* __restrict__ LAW,
                     const int* __restrict__ kpm, const int* __restrict__ em,
                     const int* __restrict__ oc, ushort* __restrict__ Ab)
{
    __shared__ __align__(16) char raw[134400];
    ushort* Ks  = (ushort*)(raw);            // 768*16 bf16   = 24576 B
    ushort* Vt  = (ushort*)(raw + 24576);    // 16*VSTR bf16  = 24832 B
    ushort* Qi  = (ushort*)(raw + 49408);    // 256*16 bf16   =  8192 B
    float*  msf = (float*) (raw + 57600);    // 768 f32       =  3072 B
    float*  LAWf= (float*) (raw + 60672);    // 16 waves * 32*LWSTR f32 = 73728 B
    ushort* As  = (ushort*)(raw);            // phase A alias: 256*72 = 36864 B
    ushort* Bs  = (ushort*)(raw + 36864);    // phase A alias: 48*72  =  6912 B
    float*  Obuf= (float*) (raw);            // post-loop alias: 256*OSTR f32 = 20480 B
    float*  Zb  = (float*) (raw + 57600);    // post-loop alias on msf: 2*256 f32
    ushort* Ob  = Qi;                        // epilogue alias (Qi dead)

    const int bh  = blockIdx.x;
    const int b   = bh & 7;        // XCD-aware: same-b blocks share an XCD L2
    const int h   = bh >> 3;
    const int tid = threadIdx.x;
    const int w   = tid >> 6;      // 0..15
    const int l   = tid & 63;

    // ======================= Phase A: QKV GEMM =======================
    const int r0 = tid >> 3;          // t-row 0..127 (also covers r0+128)
    const int c8 = tid & 7;           // 8-float chunk in the 64-k tile
    const float* Xc0 = &X[((size_t)r0 * 8 + b) * E_ + c8 * 8];
    const float* Xc1 = Xc0 + (size_t)128 * 8 * E_;

    const int wr = tid >> 3;          // valid < 48 (tid < 384)
    const bool wload = (tid < 384);   // wave-uniform (waves 0..5)
    const float* Wsel = (wr < 16) ? Wq : (wr < 32 ? Wk : Wv);
    const float* Wr = &Wsel[((size_t)(h * 16 + (wr & 15))) * E_ + c8 * 8];
    ushort* Bxw = &Bs[wr * 72 + c8 * 8];

    f32x4 acc[3];
#pragma unroll
    for (int m = 0; m < 3; ++m) acc[m] = (f32x4){0.f, 0.f, 0.f, 0.f};

    float4 xa0, xa1, xb0, xb1, wp0, wp1;
    xa0 = *(const float4*)&Xc0[0]; xa1 = *(const float4*)&Xc0[4];
    xb0 = *(const float4*)&Xc1[0]; xb1 = *(const float4*)&Xc1[4];
    if (wload) { wp0 = *(const float4*)&Wr[0]; wp1 = *(const float4*)&Wr[4]; }

    const int ln = l & 15;
    const int lg = l >> 4;

    for (int it = 0; it < 8; ++it) {
        __syncthreads();
        *(uint4*)&As[r0 * 72 + c8 * 8] =
            make_uint4(pku(xa0.x, xa0.y), pku(xa0.z, xa0.w),
                       pku(xa1.x, xa1.y), pku(xa1.z, xa1.w));
        *(uint4*)&As[(r0 + 128) * 72 + c8 * 8] =
            make_uint4(pku(xb0.x, xb0.y), pku(xb0.z, xb0.w),
                       pku(xb1.x, xb1.y), pku(xb1.z, xb1.w));
        if (wload)
            *(uint4*)&Bxw[0] = make_uint4(pku(wp0.x, wp0.y), pku(wp0.z, wp0.w),
                                          pku(wp1.x, wp1.y), pku(wp1.z, wp1.w));
        __syncthreads();
        if (it < 7) {
            Xc0 += 64; Xc1 += 64;
            xa0 = *(const float4*)&Xc0[0]; xa1 = *(const float4*)&Xc0[4];
            xb0 = *(const float4*)&Xc1[0]; xb1 = *(const float4*)&Xc1[4];
            if (wload) { Wr += 64; wp0 = *(const float4*)&Wr[0]; wp1 = *(const float4*)&Wr[4]; }
        }
#pragma unroll
        for (int kb = 0; kb < 2; ++kb) {
            bf16x8 af = *(const bf16x8*)&As[(w * 16 + ln) * 72 + kb * 32 + lg * 8];
#pragma unroll
            for (int m = 0; m < 3; ++m) {
                bf16x8 bfm = *(const bf16x8*)&Bs[(m * 16 + ln) * 72 + kb * 32 + lg * 8];
                acc[m] = __builtin_amdgcn_mfma_f32_16x16x32_bf16(af, bfm, acc[m], 0, 0, 0);
            }
        }
    }

    __syncthreads();   // As/Bs dead; image region may be written

    // ---- write Q/K/V images (C-layout: col=ln=d, row=lg*4+r) ----
    {
        const float bqv = bq[h * 16 + ln];
        const float bvv = bv[h * 16 + ln];
#pragma unroll
        for (int r = 0; r < 4; ++r) {
            const int t = w * 16 + lg * 4 + r;
            Qi[t * 16 + ln]   = bf1(acc[0][r] + bqv);
            Ks[t * 16 + ln]   = bf1(acc[1][r]);
            Vt[ln * VSTR + t] = bf1(acc[2][r] + bvv);
        }
    }

    // ---- LAW staging prologue (wave-private region; no barrier needed) ----
    const int tq = w & 7;          // t32-tile
    const int sh = w >> 3;         // s-half
    const int i0 = sh * 12;
    const int iend = i0 + 12;
    float* lws = &LAWf[w * 32 * LWSTR];
    const int srow = l >> 1;          // 0..31
    const int scol = (l & 1) * 16;    // 0 or 16
    const float* gl = &LAW[((size_t)b * T_ + tq * 32 + srow) * S_ + scol];

    float4 g0 = *(const float4*)&gl[i0 * 32 + 0];
    float4 g1 = *(const float4*)&gl[i0 * 32 + 4];
    float4 g2 = *(const float4*)&gl[i0 * 32 + 8];
    float4 g3 = *(const float4*)&gl[i0 * 32 + 12];
    *(float4*)&lws[srow * LWSTR + scol + 0]  = g0;
    *(float4*)&lws[srow * LWSTR + scol + 4]  = g1;
    *(float4*)&lws[srow * LWSTR + scol + 8]  = g2;
    *(float4*)&lws[srow * LWSTR + scol + 12] = g3;
    g0 = *(const float4*)&gl[(i0 + 1) * 32 + 0];
    g1 = *(const float4*)&gl[(i0 + 1) * 32 + 4];
    g2 = *(const float4*)&gl[(i0 + 1) * 32 + 8];
    g3 = *(const float4*)&gl[(i0 + 1) * 32 + 12];

    __syncthreads();

    // ---- expansion rows/cols 256..767 (LDS->LDS) + masks ----
    if (tid < 512) {
        const int j   = tid;
        const int src = oc[b * EXP_ + j];
        uint4 k0 = *(const uint4*)&Ks[src * 16];
        uint4 k1 = *(const uint4*)&Ks[src * 16 + 8];
        *(uint4*)&Ks[(T_ + j) * 16]     = k0;
        *(uint4*)&Ks[(T_ + j) * 16 + 8] = k1;
    } else {
        const int j   = tid - 512;
        const int src = oc[b * EXP_ + j];
#pragma unroll
        for (int d = 0; d < 16; ++d)
            Vt[d * VSTR + T_ + j] = Vt[d * VSTR + src];
    }
    if (tid < 768) {
        const int s = tid;
        const int m = (s < T_) ? kpm[b * T_ + s] : em[b * EXP_ + (s - T_)];
        msf[s] = m ? -1.0e5f : MB0_;
    }
    __syncthreads();

    // ======================= Phase B: attention =======================
    const int slane = l & 31;      // t within the wave's 32-row tile
    const int hi    = l >> 5;

    bf16x8 qf = *(const bf16x8*)&Qi[(tq * 32 + slane) * 16 + hi * 8];

    const f32x16 zero16 = {0.f,0.f,0.f,0.f,0.f,0.f,0.f,0.f,
                           0.f,0.f,0.f,0.f,0.f,0.f,0.f,0.f};
    f32x16 oacc = zero16;
    float z = 0.f;

    for (int i = i0; i < iend; ++i) {
        bf16x8 kf = *(const bf16x8*)&Ks[(i * 32 + slane) * 16 + hi * 8];
        // swapped: A=K (m=s), B=Q (n=t) -> lane holds col t=slane, rows s in regs
        f32x16 sc = __builtin_amdgcn_mfma_f32_32x32x16_bf16(kf, qf, zero16, 0, 0, 0);

#pragma unroll
        for (int ks = 0; ks < 2; ++ks) {
            float pp[8];
#pragma unroll
            for (int gi = 0; gi < 2; ++gi) {
                const int g = 2 * ks + gi;
                const float4 lw4 = *(const float4*)&lws[slane * LWSTR + g * 8 + 4 * hi];
                const float4 mb4 = *(const float4*)&msf[i * 32 + g * 8 + 4 * hi];
                const float lwa[4] = {lw4.x, lw4.y, lw4.z, lw4.w};
                const float mba[4] = {mb4.x, mb4.y, mb4.z, mb4.w};
#pragma unroll
                for (int c = 0; c < 4; ++c) {
                    const float lwv = lwa[c];
                    const float lwK = lwv * LOG2E_;
                    const float arg = __builtin_fmaf(sc[8 * ks + 4 * gi + c], lwK,
                                      __builtin_fmaf(lwK, SMOOTH_, mba[c]));
                    const float e = __builtin_amdgcn_exp2f(arg);
                    z += e;
                    pp[4 * gi + c] = e * lwv;
                }
            }
            // build PV A-frag: words w0..w3, k = hi*8 + j, s = i*32+ks*16+hi*8+j
            const unsigned int cA0 = pku(pp[0], pp[1]);
            const unsigned int cA2 = pku(pp[2], pp[3]);
            const unsigned int cB0 = pku(pp[4], pp[5]);
            const unsigned int cB2 = pku(pp[6], pp[7]);
            uint32x2 s0 = __builtin_amdgcn_permlane32_swap(cA0, cB0, false, false);
            uint32x2 s1 = __builtin_amdgcn_permlane32_swap(cA2, cB2, false, false);
            U16 u;
            u.u = make_uint4(s0.x, s1.x, s0.y, s1.y);
            bf16x8 vf = *(const bf16x8*)&Vt[(l & 15) * VSTR + i * 32 + ks * 16 + hi * 8];
            oacc = __builtin_amdgcn_mfma_f32_32x32x16_bf16(u.v, vf, oacc, 0, 0, 0);
        }

        // stage LAW tile i+1 (written after this iter's reads; wave-private)
        if (i + 1 < iend) {
            *(float4*)&lws[srow * LWSTR + scol + 0]  = g0;
            *(float4*)&lws[srow * LWSTR + scol + 4]  = g1;
            *(float4*)&lws[srow * LWSTR + scol + 8]  = g2;
            *(float4*)&lws[srow * LWSTR + scol + 12] = g3;
            if (i + 2 < iend) {
                g0 = *(const float4*)&gl[(i + 2) * 32 + 0];
                g1 = *(const float4*)&gl[(i + 2) * 32 + 4];
                g2 = *(const float4*)&gl[(i + 2) * 32 + 8];
                g3 = *(const float4*)&gl[(i + 2) * 32 + 12];
            }
        }
    }

    // z: lane holds partial for t=slane (its khalf s-subset); combine halves
    z += __shfl_xor(z, 32);

    __syncthreads();   // all waves past the loop: Ks/Vt/msf/Qi dead, alias safe

    if (l < 32) Zb[sh * 256 + tq * 32 + l] = z;

    const int dl = l & 15;
    const bool dok = (l & 31) < 16;   // cols 16..31 of oacc are duplicates
    if (sh == 1 && dok) {
#pragma unroll
        for (int r = 0; r < 16; ++r) {
            const int t = tq * 32 + (r & 3) + 8 * (r >> 2) + 4 * hi;
            Obuf[t * OSTR + dl] = oacc[r];
        }
    }
    __syncthreads();

    if (sh == 0 && dok) {
#pragma unroll
        for (int r = 0; r < 16; ++r) {
            const int t = tq * 32 + (r & 3) + 8 * (r >> 2) + 4 * hi;
            const float Zt  = Zb[t] + Zb[256 + t];
            const float inv = (Zt > 0.f) ? 1.f / Zt : 0.f;
            const float ov  = (oacc[r] + Obuf[t * OSTR + dl]) * inv;
            Ob[t * 16 + dl] = bf1(ov);
        }
    }
    __syncthreads();

    // store to Ab row-major [m][E]: m = t*8+b, cols h*16..h*16+16
    {
        const int t  = tid >> 2;
        const int q4 = tid & 3;
        *(uint2*)&Ab[((size_t)(t * 8 + b)) * E_ + h * 16 + q4 * 4] =
            *(const uint2*)&Ob[t * 16 + q4 * 4];
    }
}

// ---------------------------------------------------------------------------
// out GEMM v2: 32x64 tiles, grid (E/64, M/32) = 512 blocks -> 2 blocks/CU,
// BK=128 -> 4 K-iterations. A = Ab bf16 row-major [M][E], B = Wo fp32.
// ---------------------------------------------------------------------------
__global__ __launch_bounds__(256, 2)
void out_gemm(const ushort* __restrict__ Ab, const float* __restrict__ Wo,
              const float* __restrict__ bo, float* __restrict__ dst)
{
    __shared__ __align__(16) ushort sbuf[96 * 136];   // 26112 B
    ushort* As = sbuf;              // 32 rows x 128 k (stride 136)
    ushort* Bs = sbuf + 32 * 136;   // 64 rows x 128 k (stride 136)

    const int n0 = blockIdx.x * 64;
    const int m0 = blockIdx.y * 32;

    const int tid = threadIdx.x;
    const int arow = tid >> 3;          // 0..31
    const int acol = (tid & 7) * 16;    // 0..112
    const int brow = tid >> 2;          // 0..63
    const int bcol = (tid & 3) * 32;    // 0,32,64,96

    const ushort* Ap = &Ab[(size_t)(m0 + arow) * E_ + acol];
    const float*  Wp = &Wo[(size_t)(n0 + brow) * E_ + bcol];

    f32x4 acc[2];
    acc[0] = (f32x4){0.f, 0.f, 0.f, 0.f};
    acc[1] = (f32x4){0.f, 0.f, 0.f, 0.f};

    uint4  ha0 = *(const uint4*)&Ap[0];
    uint4  ha1 = *(const uint4*)&Ap[8];
    float4 f0 = *(const float4*)&Wp[0];
    float4 f1 = *(const float4*)&Wp[4];
    float4 f2 = *(const float4*)&Wp[8];
    float4 f3 = *(const float4*)&Wp[12];
    float4 f4 = *(const float4*)&Wp[16];
    float4 f5 = *(const float4*)&Wp[20];
    float4 f6 = *(const float4*)&Wp[24];
    float4 f7 = *(const float4*)&Wp[28];

    const int l  = tid & 63;
    const int w  = tid >> 6;
    const int wm = w & 1;          // 16-row m half
    const int wn = w >> 1;         // 32-col n half
    const int lq = l >> 4;
    const int ln = l & 15;

    for (int it = 0; it < 4; ++it) {
        __syncthreads();
        *(uint4*)&As[arow * 136 + acol]     = ha0;
        *(uint4*)&As[arow * 136 + acol + 8] = ha1;
        *(uint4*)&Bs[brow * 136 + bcol]      = make_uint4(pku(f0.x, f0.y), pku(f0.z, f0.w),
                                                          pku(f1.x, f1.y), pku(f1.z, f1.w));
        *(uint4*)&Bs[brow * 136 + bcol + 8]  = make_uint4(pku(f2.x, f2.y), pku(f2.z, f2.w),
                                                          pku(f3.x, f3.y), pku(f3.z, f3.w));
        *(uint4*)&Bs[brow * 136 + bcol + 16] = make_uint4(pku(f4.x, f4.y), pku(f4.z, f4.w),
                                                          pku(f5.x, f5.y), pku(f5.z, f5.w));
        *(uint4*)&Bs[brow * 136 + bcol + 24] = make_uint4(pku(f6.x, f6.y), pku(f6.z, f6.w),
                                                          pku(f7.x, f7.y), pku(f7.z, f7.w));
        __syncthreads();
        if (it < 3) {
            Ap += 128; Wp += 128;
            ha0 = *(const uint4*)&Ap[0];
            ha1 = *(const uint4*)&Ap[8];
            f0 = *(const float4*)&Wp[0];
            f1 = *(const float4*)&Wp[4];
            f2 = *(const float4*)&Wp[8];
            f3 = *(const float4*)&Wp[12];
            f4 = *(const float4*)&Wp[16];
            f5 = *(const float4*)&Wp[20];
            f6 = *(const float4*)&Wp[24];
            f7 = *(const float4*)&Wp[28];
        }
#pragma unroll
        for (int kb = 0; kb < 4; ++kb) {
            bf16x8 af  = *(const bf16x8*)&As[(wm * 16 + ln) * 136 + kb * 32 + lq * 8];
            bf16x8 bv0 = *(const bf16x8*)&Bs[(wn * 32 + ln) * 136 + kb * 32 + lq * 8];
            bf16x8 bv1 = *(const bf16x8*)&Bs[(wn * 32 + 16 + ln) * 136 + kb * 32 + lq * 8];
            acc[0] = __builtin_amdgcn_mfma_f32_16x16x32_bf16(af, bv0, acc[0], 0, 0, 0);
            acc[1] = __builtin_amdgcn_mfma_f32_16x16x32_bf16(af, bv1, acc[1], 0, 0, 0);
        }
    }

    const float bo0 = bo[n0 + wn * 32 + ln];
    const float bo1 = bo[n0 + wn * 32 + 16 + ln];

    __syncthreads();
    float* Lf = (float*)sbuf;       // 32 x 68 f32 = 8704 B (aliases As)
#pragma unroll
    for (int j = 0; j < 2; ++j) {
        const float bb = j ? bo1 : bo0;
        const f32x4 a = acc[j];
#pragma unroll
        for (int r = 0; r < 4; ++r)
            Lf[(wm * 16 + lq * 4 + r) * 68 + wn * 32 + j * 16 + ln] = a[r] + bb;
    }
    __syncthreads();

    {
        const int orow = tid >> 3;          // 0..31
        const int oc8  = (tid & 7) * 8;     // 0..56
        float* dp = &dst[(size_t)(m0 + orow) * E_ + n0 + oc8];
        float4 v0 = *(const float4*)&Lf[orow * 68 + oc8];
        float4 v1 = *(const float4*)&Lf[orow * 68 + oc8 + 4];
        *(float4*)&dp[0] = v0;
        *(float4*)&dp[4] = v1;
    }
}

// ---------------------------------------------------------------------------
extern "C" void kernel_launch(void* const* d_in, const int* in_sizes, int n_in,
                              void* d_out, int out_size, void* d_ws, size_t ws_size,
                              hipStream_t stream)
{
    const float* query = (const float*)d_in[0];
    const int*   oc    = (const int*)d_in[1];
    const int*   em    = (const int*)d_in[2];
    const int*   kpm   = (const int*)d_in[3];
    const float* law   = (const float*)d_in[4];
    const float* Wq    = (const float*)d_in[5];
    const float* bq    = (const float*)d_in[6];
    const float* Wk    = (const float*)d_in[7];
    const float* Wv    = (const float*)d_in[8];
    const float* bv    = (const float*)d_in[9];
    const float* Wo    = (const float*)d_in[10];
    const float* bo    = (const float*)d_in[11];
    float* out = (float*)d_out;

    ushort* Ab = (ushort*)d_ws;     // row-major [M][E] bf16

    qkv_attn_kernel<<<B_ * H_, 1024, 0, stream>>>(query, Wq, Wk, Wv, bq, bv,
                                                  law, kpm, em, oc, Ab);

    dim3 go(E_ / 64, M_ / 32, 1);
    out_gemm<<<go, 256, 0, stream>>>(Ab, Wo, bo, out);
}